// Round 19
// baseline (247.760 us; speedup 1.0000x reference)
//
#include <hip/hip_runtime.h>
#include <hip/hip_bf16.h>
#include <math.h>

#define BATCH 2
#define NPT   8192
#define DIMC  128
#define NH    4
#define KNN_K 16
#define HID   32
#define BN    (BATCH*NPT)   // 16384

// ---------------------------------------------------------------------------
// Fused Kernel 1: KNN ∥ QKV, RESIDENCY-MATCHED (round-19).
// r17's 3072-block fusion couldn't overlap: only 2048 blocks are resident
// (8/CU x 256 CUs); the queued 1/3 included knn blocks whose late start
// appended a ~40 µs stagger tail (146 ≈ 107+40, no overlap). Fix: knn at
// QPW=4 (16 queries/block -> 1024 blocks, same total work, same 32
// waves/CU) + 1024 qkv blocks = 2048 = exact residency. g&1 mapping.
// Per-query knn math/insert logic and the qkv body are instruction-
// identical to proven versions -> bit-identical results.
// ---------------------------------------------------------------------------
#define TILE 1024
#define QPW  4
#define NWV  4
#define KNNB (BN/(NWV*QPW))      // 1024
#define QKVB (BN/16)             // 1024 (16 rows/block, 2 rows/thread)

__device__ __forceinline__ float readlane_f(float v, int l) {
  return __int_as_float(__builtin_amdgcn_readlane(__float_as_int(v), l));
}
// DPP row_shr:1 — lane i reads lane i-1 within its 16-lane row (VALU pipe).
__device__ __forceinline__ float dpp_shr1_f(float x) {
  return __int_as_float(__builtin_amdgcn_update_dpp(
      __float_as_int(x), __float_as_int(x), 0x111, 0xF, 0xF, false));
}
__device__ __forceinline__ int dpp_shr1_i(int x) {
  return __builtin_amdgcn_update_dpp(x, x, 0x111, 0xF, 0xF, false);
}
__device__ __forceinline__ float f4c(const float4 v, int u) {
  return u == 0 ? v.x : u == 1 ? v.y : u == 2 ? v.z : v.w;
}

__global__ __launch_bounds__(256) void knnqkv_kernel(
    const float* __restrict__ xyz, int* __restrict__ knn_out,
    const float* __restrict__ x,
    const float* __restrict__ Wq, const float* __restrict__ bq,
    const float* __restrict__ Wk, const float* __restrict__ bk,
    const float* __restrict__ Wv, const float* __restrict__ bv,
    float* __restrict__ q, float* __restrict__ k, float* __restrict__ v) {
  __shared__ float4 sbuf[TILE];   // 16 KB, shared by both paths
  const int g   = blockIdx.x;
  const int tid = threadIdx.x;

  if ((g & 1) == 0) {
    // =================== KNN path (QPW=4, 1024 blocks) ===================
    const int kb_  = g >> 1;
    const int lane = tid & 63;
    const int wave = tid >> 6;
    const int qbase = kb_ * (NWV*QPW) + wave * QPW;
    const int b = qbase / NPT;

    float qx[QPW], qy[QPW], qz[QPW], qsq[QPW];
    float topd[QPW]; int topi[QPW]; float tau[QPW];
#pragma unroll
    for (int qi = 0; qi < QPW; ++qi) {
      const int gg = qbase + qi;
      qx[qi] = xyz[(size_t)gg*3+0];
      qy[qi] = xyz[(size_t)gg*3+1];
      qz[qi] = xyz[(size_t)gg*3+2];
      qsq[qi] = __fadd_rn(__fadd_rn(__fmul_rn(qx[qi],qx[qi]),
                                    __fmul_rn(qy[qi],qy[qi])),
                          __fmul_rn(qz[qi],qz[qi]));
      topd[qi] = 3e38f; topi[qi] = 0; tau[qi] = 3e38f;
    }

    for (int t = 0; t < NPT/TILE; ++t) {
      __syncthreads();
      const float* src = xyz + (size_t)(b*NPT + t*TILE)*3;
      for (int i = tid; i < TILE; i += 256) {
        const float xx = src[i*3+0], yy = src[i*3+1], zz = src[i*3+2];
        const float sq = __fadd_rn(__fadd_rn(__fmul_rn(xx,xx), __fmul_rn(yy,yy)),
                                   __fmul_rn(zz,zz));
        sbuf[i] = make_float4(xx+xx, yy+yy, zz+zz, sq);
      }
      __syncthreads();

      for (int c = 0; c < TILE/64; ++c) {
        const float4 cd = sbuf[c*64 + lane];
        const int cbase = t*TILE + c*64;
#pragma unroll
        for (int qi = 0; qi < QPW; ++qi) {
          float dot2 = __fadd_rn(__fadd_rn(__fmul_rn(qx[qi],cd.x),
                                           __fmul_rn(qy[qi],cd.y)),
                                 __fmul_rn(qz[qi],cd.z));
          float d2 = __fsub_rn(__fadd_rn(qsq[qi], cd.w), dot2);
          unsigned long long m = __ballot(d2 < tau[qi]);
          while (m) {
            const int l = (int)__builtin_ctzll(m);
            const float dn = readlane_f(d2, l);
            const int   ni_ = cbase + l;
            const float my  = topd[qi];
            const int   myi = topi[qi];
            float ab  = dpp_shr1_f(my);
            int   abi = dpp_shr1_i(myi);
            if (lane == 0) ab = -3e38f;
            const bool ge = dn < my;
            const bool gt = dn < ab;
            topd[qi] = ge ? (gt ? ab  : dn ) : my;
            topi[qi] = ge ? (gt ? abi : ni_) : myi;
            tau[qi] = readlane_f(topd[qi], 15);
            m &= (m - 1);
            if (m) m &= __ballot(d2 < tau[qi]);
          }
        }
      }
    }

#pragma unroll
    for (int qi = 0; qi < QPW; ++qi) {
      if (lane < KNN_K) knn_out[(size_t)(qbase + qi)*KNN_K + lane] = topi[qi];
    }
  } else {
    // =================== QKV path (r5 body, 1024 blocks) ===================
    float* xs = (float*)sbuf;       // 16 rows x 128 = 8 KB
    const int qb_ = g >> 1;
    const int rowbase = qb_ * 16;
    {
      float4* xs4 = (float4*)xs;
      const float4* src4 = (const float4*)(x + (size_t)rowbase*DIMC);
      for (int i = tid; i < 16*DIMC/4; i += 256) xs4[i] = src4[i];
    }
    __syncthreads();

    const int cg = tid & 31, rg = tid >> 5;
    const int c0 = cg * 4;
    float4 aq0 = *(const float4*)&bq[c0], aq1 = aq0;
    float4 ak0 = *(const float4*)&bk[c0], ak1 = ak0;
    float4 av0 = *(const float4*)&bv[c0], av1 = av0;

    for (int kk = 0; kk < DIMC; kk += 4) {
      const float4 xa = *(const float4*)&xs[rg*DIMC + kk];
      const float4 xb = *(const float4*)&xs[(rg+8)*DIMC + kk];
#pragma unroll
      for (int u = 0; u < 4; ++u) {
        const float4 wq = *(const float4*)&Wq[(size_t)(kk+u)*DIMC + c0];
        const float4 wk = *(const float4*)&Wk[(size_t)(kk+u)*DIMC + c0];
        const float4 wv = *(const float4*)&Wv[(size_t)(kk+u)*DIMC + c0];
        const float xau = f4c(xa, u), xbu = f4c(xb, u);
        aq0.x = fmaf(xau, wq.x, aq0.x); aq0.y = fmaf(xau, wq.y, aq0.y);
        aq0.z = fmaf(xau, wq.z, aq0.z); aq0.w = fmaf(xau, wq.w, aq0.w);
        aq1.x = fmaf(xbu, wq.x, aq1.x); aq1.y = fmaf(xbu, wq.y, aq1.y);
        aq1.z = fmaf(xbu, wq.z, aq1.z); aq1.w = fmaf(xbu, wq.w, aq1.w);
        ak0.x = fmaf(xau, wk.x, ak0.x); ak0.y = fmaf(xau, wk.y, ak0.y);
        ak0.z = fmaf(xau, wk.z, ak0.z); ak0.w = fmaf(xau, wk.w, ak0.w);
        ak1.x = fmaf(xbu, wk.x, ak1.x); ak1.y = fmaf(xbu, wk.y, ak1.y);
        ak1.z = fmaf(xbu, wk.z, ak1.z); ak1.w = fmaf(xbu, wk.w, ak1.w);
        av0.x = fmaf(xau, wv.x, av0.x); av0.y = fmaf(xau, wv.y, av0.y);
        av0.z = fmaf(xau, wv.z, av0.z); av0.w = fmaf(xau, wv.w, av0.w);
        av1.x = fmaf(xbu, wv.x, av1.x); av1.y = fmaf(xbu, wv.y, av1.y);
        av1.z = fmaf(xbu, wv.z, av1.z); av1.w = fmaf(xbu, wv.w, av1.w);
      }
    }

    const size_t r0 = (size_t)(rowbase + rg)*DIMC + c0;
    const size_t r1 = (size_t)(rowbase + rg + 8)*DIMC + c0;
    *(float4*)&q[r0] = aq0; *(float4*)&q[r1] = aq1;
    *(float4*)&k[r0] = ak0; *(float4*)&k[r1] = ak1;
    *(float4*)&v[r0] = av0; *(float4*)&v[r1] = av1;
  }
}

// ---------------------------------------------------------------------------
// DPP ring-rotate move (VALU, no DS pipe): lane i of each 16-lane row reads
// lane (i+N)%16. Ring all-reduce with N=1,2,4,8 covers all 16 lanes.
// ---------------------------------------------------------------------------
template <int CTRL>
__device__ __forceinline__ float dppf(float x) {
  return __int_as_float(__builtin_amdgcn_update_dpp(
      __float_as_int(x), __float_as_int(x), CTRL, 0xF, 0xF, false));
}
#define ROR1 0x121
#define ROR2 0x122
#define ROR4 0x124
#define ROR8 0x128

// ---------------------------------------------------------------------------
// Kernel 2: gather + bias MLP + attention. ONE WAVE PER POINT.
// (r17 version, unchanged)
// ---------------------------------------------------------------------------
__global__ __launch_bounds__(256) void attn_kernel(const float* __restrict__ xyz,
    const int* __restrict__ knn, const float* __restrict__ qb,
    const float* __restrict__ kb, const float* __restrict__ vb,
    const float* __restrict__ W1, const float* __restrict__ b1,
    const float* __restrict__ W2, const float* __restrict__ b2,
    float* __restrict__ ao) {
  __shared__ float sw[4][NH][KNN_K];
  __shared__ int   sn[4][KNN_K];
  const int tid  = threadIdx.x;
  const int wave = tid >> 6;
  const int lane = tid & 63;
  const int p = blockIdx.x * 4 + wave;
  const int b = p / NPT;
  const int h = lane >> 4;
  const int j = lane & 15;

  const int nj = knn[(size_t)p*KNN_K + j];
  if (h == 0) sn[wave][j] = nj;
  const size_t nn = (size_t)b*NPT + nj;

  // bias MLP for this lane's (h, j)
  const float qx0 = xyz[(size_t)p*3+0];
  const float qy0 = xyz[(size_t)p*3+1];
  const float qz0 = xyz[(size_t)p*3+2];
  const float rx = qx0 - xyz[nn*3+0];
  const float ry = qy0 - xyz[nn*3+1];
  const float rz = qz0 - xyz[nn*3+2];
  float bias = b2[h];
#pragma unroll 8
  for (int u = 0; u < HID; ++u) {
    float hv = rx*W1[0*HID+u] + ry*W1[1*HID+u] + rz*W1[2*HID+u] + b1[u];
    hv = hv > 0.f ? hv : 0.f;
    bias = fmaf(hv, W2[u*NH + h], bias);
  }

  // score: q[p,h,:] · k[nj,h,:]  (32 channels, 8x float4 each side)
  const float* qrow = qb + (size_t)p*DIMC + h*32;
  const float* krow = kb + nn*DIMC + h*32;
  float s = 0.f;
#pragma unroll
  for (int u = 0; u < 32; u += 4) {
    const float4 qv = *(const float4*)(qrow + u);
    const float4 kv = *(const float4*)(krow + u);
    s = fmaf(qv.x, kv.x, s); s = fmaf(qv.y, kv.y, s);
    s = fmaf(qv.z, kv.z, s); s = fmaf(qv.w, kv.w, s);
  }
  s = s * 0.17677669529663689f + bias;   // 1/sqrt(32)

  // softmax over the 16-lane j-group: DPP ring all-reduce (max, then sum)
  float m = s;
  m = fmaxf(m, dppf<ROR1>(m));
  m = fmaxf(m, dppf<ROR2>(m));
  m = fmaxf(m, dppf<ROR4>(m));
  m = fmaxf(m, dppf<ROR8>(m));
  const float e = expf(s - m);
  float ssum = e;
  ssum += dppf<ROR1>(ssum);
  ssum += dppf<ROR2>(ssum);
  ssum += dppf<ROR4>(ssum);
  ssum += dppf<ROR8>(ssum);
  sw[wave][h][j] = e / ssum;

  __syncthreads();

  // phase B: lane = channel d0 (and d0+64); weighted sum of v rows
  const int d0 = lane;
  const int hA = d0 >> 5;              // head of channel d0 (0 or 1)
  float out0 = 0.f, out1 = 0.f;
  const float* vbase = vb + (size_t)b*NPT*DIMC;
#pragma unroll 4
  for (int j2 = 0; j2 < KNN_K; ++j2) {
    const int n = sn[wave][j2];
    const float wA = sw[wave][hA][j2];
    const float wB = sw[wave][2+hA][j2];
    const float* vrow = vbase + (size_t)n*DIMC;
    out0 = fmaf(wA, vrow[d0],    out0);
    out1 = fmaf(wB, vrow[64+d0], out1);
  }
  ao[(size_t)p*DIMC + d0]      = out0;
  ao[(size_t)p*DIMC + 64 + d0] = out1;
}

// ---------------------------------------------------------------------------
// Kernel 3: output projection, 4 rows/thread, 16 rows/block, IN-PLACE on
// d_out. (r13/r17 version, unchanged)
// ---------------------------------------------------------------------------
#define PROJ_ROWS 16

__global__ __launch_bounds__(128) void proj_kernel(float* __restrict__ inout,
    const float* __restrict__ Wo, const float* __restrict__ bo) {
  __shared__ float xs[PROJ_ROWS*DIMC];   // 8 KB
  const int tid = threadIdx.x;
  const int rowbase = blockIdx.x * PROJ_ROWS;
  {
    float4* xs4 = (float4*)xs;
    const float4* src4 = (const float4*)(inout + (size_t)rowbase*DIMC);
    for (int i = tid; i < PROJ_ROWS*DIMC/4; i += 128) xs4[i] = src4[i];
  }
  __syncthreads();

  const int cg = tid & 31, rg = tid >> 5;   // rg 0..3
  const int c0 = cg * 4;
  float4 a[4];
  {
    const float4 bo4 = *(const float4*)&bo[c0];
#pragma unroll
    for (int i = 0; i < 4; ++i) a[i] = bo4;
  }

  for (int kk = 0; kk < DIMC; kk += 4) {
    float4 xr[4];
#pragma unroll
    for (int i = 0; i < 4; ++i)
      xr[i] = *(const float4*)&xs[(rg + 4*i)*DIMC + kk];
#pragma unroll
    for (int u = 0; u < 4; ++u) {
      const float4 w = *(const float4*)&Wo[(size_t)(kk+u)*DIMC + c0];
#pragma unroll
      for (int i = 0; i < 4; ++i) {
        const float xv = f4c(xr[i], u);
        a[i].x = fmaf(xv, w.x, a[i].x); a[i].y = fmaf(xv, w.y, a[i].y);
        a[i].z = fmaf(xv, w.z, a[i].z); a[i].w = fmaf(xv, w.w, a[i].w);
      }
    }
  }

#pragma unroll
  for (int i = 0; i < 4; ++i)
    *(float4*)&inout[(size_t)(rowbase + rg + 4*i)*DIMC + c0] = a[i];
}

// ---------------------------------------------------------------------------
extern "C" void kernel_launch(void* const* d_in, const int* in_sizes, int n_in,
                              void* d_out, int out_size, void* d_ws, size_t ws_size,
                              hipStream_t stream) {
  const float* x   = (const float*)d_in[0];
  const float* xyz = (const float*)d_in[1];
  const float* Wq  = (const float*)d_in[2];
  const float* bq  = (const float*)d_in[3];
  const float* Wk  = (const float*)d_in[4];
  const float* bk  = (const float*)d_in[5];
  const float* Wv  = (const float*)d_in[6];
  const float* bv  = (const float*)d_in[7];
  const float* Wo  = (const float*)d_in[8];
  const float* bo  = (const float*)d_in[9];
  const float* W1  = (const float*)d_in[10];
  const float* b1  = (const float*)d_in[11];
  const float* W2  = (const float*)d_in[12];
  const float* b2  = (const float*)d_in[13];
  float* out = (float*)d_out;

  // workspace layout (bytes): knn idx 1MB | q 8MB | k 8MB | v 8MB  => 25MB
  char* ws = (char*)d_ws;
  int*   knn = (int*)ws;
  float* q   = (float*)(ws + (size_t)(1u<<20));
  float* k   = (float*)(ws + (size_t)9*(1u<<20));
  float* v   = (float*)(ws + (size_t)17*(1u<<20));

  // grid = KNNB + QKVB = 2048 exactly = full residency (8 blocks/CU x 256)
  hipLaunchKernelGGL(knnqkv_kernel, dim3(KNNB + QKVB), dim3(256), 0, stream,
                     xyz, knn, x, Wq, bq, Wk, bk, Wv, bv, q, k, v);
  hipLaunchKernelGGL(attn_kernel, dim3(BN/4), dim3(256), 0, stream,
                     xyz, knn, q, k, v, W1, b1, W2, b2, out);
  hipLaunchKernelGGL(proj_kernel, dim3(BN/PROJ_ROWS), dim3(128), 0, stream,
                     out, Wo, bo);
}

// Round 20
// 204.481 us; speedup vs baseline: 1.2117x; 1.2117x over previous
//
#include <hip/hip_runtime.h>
#include <hip/hip_bf16.h>
#include <math.h>

#define BATCH 2
#define NPT   8192
#define DIMC  128
#define NH    4
#define KNN_K 16
#define HID   32
#define BN    (BATCH*NPT)   // 16384

// ---------------------------------------------------------------------------
// Kernel 1: exact 16-NN full scan (r13 proven: 107 µs, VALUBusy 82%,
// issue-bound). QPW=2, 2048 blocks, DPP insert shifts. Standalone again:
// r17/r19 proved fusion cannot help an issue-bound kernel (qkv waves just
// steal issue slots 1:1).
// ---------------------------------------------------------------------------
#define TILE 1024
#define QPW  2
#define NWV  4

__device__ __forceinline__ float readlane_f(float v, int l) {
  return __int_as_float(__builtin_amdgcn_readlane(__float_as_int(v), l));
}
__device__ __forceinline__ float dpp_shr1_f(float x) {
  return __int_as_float(__builtin_amdgcn_update_dpp(
      __float_as_int(x), __float_as_int(x), 0x111, 0xF, 0xF, false));
}
__device__ __forceinline__ int dpp_shr1_i(int x) {
  return __builtin_amdgcn_update_dpp(x, x, 0x111, 0xF, 0xF, false);
}
__device__ __forceinline__ float f4c(const float4 v, int u) {
  return u == 0 ? v.x : u == 1 ? v.y : u == 2 ? v.z : v.w;
}

__global__ __launch_bounds__(256) void knn_kernel(const float* __restrict__ xyz,
                                                  int* __restrict__ knn_out) {
  __shared__ float4 spts[TILE];   // 16 KB
  const int tid  = threadIdx.x;
  const int lane = tid & 63;
  const int wave = tid >> 6;
  const int qbase = blockIdx.x * (NWV*QPW) + wave * QPW;
  const int b = qbase / NPT;

  float qx[QPW], qy[QPW], qz[QPW], qsq[QPW];
  float topd[QPW]; int topi[QPW]; float tau[QPW];
#pragma unroll
  for (int qi = 0; qi < QPW; ++qi) {
    const int g = qbase + qi;
    qx[qi] = xyz[(size_t)g*3+0];
    qy[qi] = xyz[(size_t)g*3+1];
    qz[qi] = xyz[(size_t)g*3+2];
    qsq[qi] = __fadd_rn(__fadd_rn(__fmul_rn(qx[qi],qx[qi]),
                                  __fmul_rn(qy[qi],qy[qi])),
                        __fmul_rn(qz[qi],qz[qi]));
    topd[qi] = 3e38f; topi[qi] = 0; tau[qi] = 3e38f;
  }

  for (int t = 0; t < NPT/TILE; ++t) {
    __syncthreads();
    const float* src = xyz + (size_t)(b*NPT + t*TILE)*3;
    for (int i = tid; i < TILE; i += 256) {
      const float x = src[i*3+0], y = src[i*3+1], z = src[i*3+2];
      const float sq = __fadd_rn(__fadd_rn(__fmul_rn(x,x), __fmul_rn(y,y)),
                                 __fmul_rn(z,z));
      spts[i] = make_float4(x+x, y+y, z+z, sq);
    }
    __syncthreads();

    for (int c = 0; c < TILE/64; ++c) {
      const float4 cd = spts[c*64 + lane];
      const int cbase = t*TILE + c*64;
#pragma unroll
      for (int qi = 0; qi < QPW; ++qi) {
        float dot2 = __fadd_rn(__fadd_rn(__fmul_rn(qx[qi],cd.x),
                                         __fmul_rn(qy[qi],cd.y)),
                               __fmul_rn(qz[qi],cd.z));
        float d2 = __fsub_rn(__fadd_rn(qsq[qi], cd.w), dot2);
        unsigned long long m = __ballot(d2 < tau[qi]);
        while (m) {
          const int l = (int)__builtin_ctzll(m);
          const float dn = readlane_f(d2, l);
          const int   ni_ = cbase + l;
          const float my  = topd[qi];
          const int   myi = topi[qi];
          float ab  = dpp_shr1_f(my);
          int   abi = dpp_shr1_i(myi);
          if (lane == 0) ab = -3e38f;
          const bool ge = dn < my;
          const bool gt = dn < ab;
          topd[qi] = ge ? (gt ? ab  : dn ) : my;
          topi[qi] = ge ? (gt ? abi : ni_) : myi;
          tau[qi] = readlane_f(topd[qi], 15);
          m &= (m - 1);
          if (m) m &= __ballot(d2 < tau[qi]);
        }
      }
    }
  }

#pragma unroll
  for (int qi = 0; qi < QPW; ++qi) {
    if (lane < KNN_K) knn_out[(size_t)(qbase + qi)*KNN_K + lane] = topi[qi];
  }
}

// ---------------------------------------------------------------------------
// Kernel 2: fused Q/K/V projection with LDS W-TILE STAGING (round-20).
// Old qkv: each thread issued 384 float4 W loads from L2 (~200 cy) with 2
// waves/SIMD — latency-bound, ~40 µs for a 13 µs-VALU GEMM. New: per 8-row
// kk-tile, the 128 threads cooperatively stage Wq/Wk/Wv rows (12 KB,
// coalesced float4), barrier, then FMAs read LDS (lane 32-63 mirror lane
// 0-31 addresses -> broadcast, conflict-free). Thread owns rows {rg+4i} x
// cols [4cg,4cg+4) x 3 mats = 48 acc. FMA order per output stays
// kk-ascending with identical W bits -> bit-identical results.
// LDS 8+12=20 KB -> 8 blocks/CU possible; grid 1024.
// ---------------------------------------------------------------------------
#define QKV_ROWS 16
#define WTILE    8

__global__ __launch_bounds__(128) void qkv_kernel(const float* __restrict__ x,
    const float* __restrict__ Wq, const float* __restrict__ bq,
    const float* __restrict__ Wk, const float* __restrict__ bk,
    const float* __restrict__ Wv, const float* __restrict__ bv,
    float* __restrict__ q, float* __restrict__ k, float* __restrict__ v) {
  __shared__ float xs[QKV_ROWS*DIMC];      // 8 KB
  __shared__ float wt[3][WTILE][DIMC];     // 12 KB
  const int tid = threadIdx.x;
  const int rowbase = blockIdx.x * QKV_ROWS;
  {
    float4* xs4 = (float4*)xs;
    const float4* src4 = (const float4*)(x + (size_t)rowbase*DIMC);
    for (int i = tid; i < QKV_ROWS*DIMC/4; i += 128) xs4[i] = src4[i];
  }

  const int cg = tid & 31, rg = tid >> 5;   // rg 0..3
  const int c0 = cg * 4;
  float4 aq[4], ak[4], av[4];
  {
    const float4 bq4 = *(const float4*)&bq[c0];
    const float4 bk4 = *(const float4*)&bk[c0];
    const float4 bv4 = *(const float4*)&bv[c0];
#pragma unroll
    for (int i = 0; i < 4; ++i) { aq[i] = bq4; ak[i] = bk4; av[i] = bv4; }
  }

  for (int kt = 0; kt < DIMC; kt += WTILE) {
    __syncthreads();   // (a) xs ready on first iter; (b) wt consumed on later
    // stage W tile: 3 mats x 8 rows x 128 cols = 768 float4, 6 per thread
    for (int i = tid; i < 3*WTILE*DIMC/4; i += 128) {
      const int m  = i >> 8;            // i / 256
      const int rr = (i >> 5) & 7;      // (i % 256) / 32
      const int cc = (i & 31) << 2;
      const float* Wsrc = (m == 0) ? Wq : (m == 1) ? Wk : Wv;
      *(float4*)&wt[m][rr][cc] =
          *(const float4*)&Wsrc[(size_t)(kt+rr)*DIMC + cc];
    }
    __syncthreads();

#pragma unroll
    for (int u = 0; u < WTILE; ++u) {
      const float4 wq4 = *(const float4*)&wt[0][u][c0];
      const float4 wk4 = *(const float4*)&wt[1][u][c0];
      const float4 wv4 = *(const float4*)&wt[2][u][c0];
#pragma unroll
      for (int i = 0; i < 4; ++i) {
        const float xv = xs[(rg + 4*i)*DIMC + kt + u];
        aq[i].x = fmaf(xv, wq4.x, aq[i].x); aq[i].y = fmaf(xv, wq4.y, aq[i].y);
        aq[i].z = fmaf(xv, wq4.z, aq[i].z); aq[i].w = fmaf(xv, wq4.w, aq[i].w);
        ak[i].x = fmaf(xv, wk4.x, ak[i].x); ak[i].y = fmaf(xv, wk4.y, ak[i].y);
        ak[i].z = fmaf(xv, wk4.z, ak[i].z); ak[i].w = fmaf(xv, wk4.w, ak[i].w);
        av[i].x = fmaf(xv, wv4.x, av[i].x); av[i].y = fmaf(xv, wv4.y, av[i].y);
        av[i].z = fmaf(xv, wv4.z, av[i].z); av[i].w = fmaf(xv, wv4.w, av[i].w);
      }
    }
  }

#pragma unroll
  for (int i = 0; i < 4; ++i) {
    const size_t rr = (size_t)(rowbase + rg + 4*i)*DIMC + c0;
    *(float4*)&q[rr] = aq[i];
    *(float4*)&k[rr] = ak[i];
    *(float4*)&v[rr] = av[i];
  }
}

// ---------------------------------------------------------------------------
// DPP ring-rotate move (VALU, no DS pipe).
// ---------------------------------------------------------------------------
template <int CTRL>
__device__ __forceinline__ float dppf(float x) {
  return __int_as_float(__builtin_amdgcn_update_dpp(
      __float_as_int(x), __float_as_int(x), CTRL, 0xF, 0xF, false));
}
#define ROR1 0x121
#define ROR2 0x122
#define ROR4 0x124
#define ROR8 0x128

// ---------------------------------------------------------------------------
// Kernel 3: gather + bias MLP + attention. ONE WAVE PER POINT. (unchanged)
// ---------------------------------------------------------------------------
__global__ __launch_bounds__(256) void attn_kernel(const float* __restrict__ xyz,
    const int* __restrict__ knn, const float* __restrict__ qb,
    const float* __restrict__ kb, const float* __restrict__ vb,
    const float* __restrict__ W1, const float* __restrict__ b1,
    const float* __restrict__ W2, const float* __restrict__ b2,
    float* __restrict__ ao) {
  __shared__ float sw[4][NH][KNN_K];
  __shared__ int   sn[4][KNN_K];
  const int tid  = threadIdx.x;
  const int wave = tid >> 6;
  const int lane = tid & 63;
  const int p = blockIdx.x * 4 + wave;
  const int b = p / NPT;
  const int h = lane >> 4;
  const int j = lane & 15;

  const int nj = knn[(size_t)p*KNN_K + j];
  if (h == 0) sn[wave][j] = nj;
  const size_t nn = (size_t)b*NPT + nj;

  const float qx0 = xyz[(size_t)p*3+0];
  const float qy0 = xyz[(size_t)p*3+1];
  const float qz0 = xyz[(size_t)p*3+2];
  const float rx = qx0 - xyz[nn*3+0];
  const float ry = qy0 - xyz[nn*3+1];
  const float rz = qz0 - xyz[nn*3+2];
  float bias = b2[h];
#pragma unroll 8
  for (int u = 0; u < HID; ++u) {
    float hv = rx*W1[0*HID+u] + ry*W1[1*HID+u] + rz*W1[2*HID+u] + b1[u];
    hv = hv > 0.f ? hv : 0.f;
    bias = fmaf(hv, W2[u*NH + h], bias);
  }

  const float* qrow = qb + (size_t)p*DIMC + h*32;
  const float* krow = kb + nn*DIMC + h*32;
  float s = 0.f;
#pragma unroll
  for (int u = 0; u < 32; u += 4) {
    const float4 qv = *(const float4*)(qrow + u);
    const float4 kv = *(const float4*)(krow + u);
    s = fmaf(qv.x, kv.x, s); s = fmaf(qv.y, kv.y, s);
    s = fmaf(qv.z, kv.z, s); s = fmaf(qv.w, kv.w, s);
  }
  s = s * 0.17677669529663689f + bias;   // 1/sqrt(32)

  float m = s;
  m = fmaxf(m, dppf<ROR1>(m));
  m = fmaxf(m, dppf<ROR2>(m));
  m = fmaxf(m, dppf<ROR4>(m));
  m = fmaxf(m, dppf<ROR8>(m));
  const float e = expf(s - m);
  float ssum = e;
  ssum += dppf<ROR1>(ssum);
  ssum += dppf<ROR2>(ssum);
  ssum += dppf<ROR4>(ssum);
  ssum += dppf<ROR8>(ssum);
  sw[wave][h][j] = e / ssum;

  __syncthreads();

  const int d0 = lane;
  const int hA = d0 >> 5;
  float out0 = 0.f, out1 = 0.f;
  const float* vbase = vb + (size_t)b*NPT*DIMC;
#pragma unroll 4
  for (int j2 = 0; j2 < KNN_K; ++j2) {
    const int n = sn[wave][j2];
    const float wA = sw[wave][hA][j2];
    const float wB = sw[wave][2+hA][j2];
    const float* vrow = vbase + (size_t)n*DIMC;
    out0 = fmaf(wA, vrow[d0],    out0);
    out1 = fmaf(wB, vrow[64+d0], out1);
  }
  ao[(size_t)p*DIMC + d0]      = out0;
  ao[(size_t)p*DIMC + 64 + d0] = out1;
}

// ---------------------------------------------------------------------------
// Kernel 4: output projection, 4 rows/thread, 16 rows/block, IN-PLACE on
// d_out. (r13 version, unchanged)
// ---------------------------------------------------------------------------
#define PROJ_ROWS 16

__global__ __launch_bounds__(128) void proj_kernel(float* __restrict__ inout,
    const float* __restrict__ Wo, const float* __restrict__ bo) {
  __shared__ float xs[PROJ_ROWS*DIMC];   // 8 KB
  const int tid = threadIdx.x;
  const int rowbase = blockIdx.x * PROJ_ROWS;
  {
    float4* xs4 = (float4*)xs;
    const float4* src4 = (const float4*)(inout + (size_t)rowbase*DIMC);
    for (int i = tid; i < PROJ_ROWS*DIMC/4; i += 128) xs4[i] = src4[i];
  }
  __syncthreads();

  const int cg = tid & 31, rg = tid >> 5;   // rg 0..3
  const int c0 = cg * 4;
  float4 a[4];
  {
    const float4 bo4 = *(const float4*)&bo[c0];
#pragma unroll
    for (int i = 0; i < 4; ++i) a[i] = bo4;
  }

  for (int kk = 0; kk < DIMC; kk += 4) {
    float4 xr[4];
#pragma unroll
    for (int i = 0; i < 4; ++i)
      xr[i] = *(const float4*)&xs[(rg + 4*i)*DIMC + kk];
#pragma unroll
    for (int u = 0; u < 4; ++u) {
      const float4 w = *(const float4*)&Wo[(size_t)(kk+u)*DIMC + c0];
#pragma unroll
      for (int i = 0; i < 4; ++i) {
        const float xv = f4c(xr[i], u);
        a[i].x = fmaf(xv, w.x, a[i].x); a[i].y = fmaf(xv, w.y, a[i].y);
        a[i].z = fmaf(xv, w.z, a[i].z); a[i].w = fmaf(xv, w.w, a[i].w);
      }
    }
  }

#pragma unroll
  for (int i = 0; i < 4; ++i)
    *(float4*)&inout[(size_t)(rowbase + rg + 4*i)*DIMC + c0] = a[i];
}

// ---------------------------------------------------------------------------
extern "C" void kernel_launch(void* const* d_in, const int* in_sizes, int n_in,
                              void* d_out, int out_size, void* d_ws, size_t ws_size,
                              hipStream_t stream) {
  const float* x   = (const float*)d_in[0];
  const float* xyz = (const float*)d_in[1];
  const float* Wq  = (const float*)d_in[2];
  const float* bq  = (const float*)d_in[3];
  const float* Wk  = (const float*)d_in[4];
  const float* bk  = (const float*)d_in[5];
  const float* Wv  = (const float*)d_in[6];
  const float* bv  = (const float*)d_in[7];
  const float* Wo  = (const float*)d_in[8];
  const float* bo  = (const float*)d_in[9];
  const float* W1  = (const float*)d_in[10];
  const float* b1  = (const float*)d_in[11];
  const float* W2  = (const float*)d_in[12];
  const float* b2  = (const float*)d_in[13];
  float* out = (float*)d_out;

  // workspace layout (bytes): knn idx 1MB | q 8MB | k 8MB | v 8MB  => 25MB
  char* ws = (char*)d_ws;
  int*   knn = (int*)ws;
  float* q   = (float*)(ws + (size_t)(1u<<20));
  float* k   = (float*)(ws + (size_t)9*(1u<<20));
  float* v   = (float*)(ws + (size_t)17*(1u<<20));

  hipLaunchKernelGGL(knn_kernel, dim3(BN/(NWV*QPW)), dim3(256), 0, stream, xyz, knn);
  hipLaunchKernelGGL(qkv_kernel, dim3(BN/QKV_ROWS), dim3(128), 0, stream,
                     x, Wq, bq, Wk, bk, Wv, bv, q, k, v);
  hipLaunchKernelGGL(attn_kernel, dim3(BN/4), dim3(256), 0, stream,
                     xyz, knn, q, k, v, W1, b1, W2, b2, out);
  hipLaunchKernelGGL(proj_kernel, dim3(BN/PROJ_ROWS), dim3(128), 0, stream,
                     out, Wo, bo);
}

// Round 21
// 188.045 us; speedup vs baseline: 1.3176x; 1.0874x over previous
//
#include <hip/hip_runtime.h>
#include <hip/hip_bf16.h>
#include <math.h>

#define BATCH 2
#define NPT   8192
#define DIMC  128
#define NH    4
#define KNN_K 16
#define HID   32
#define BN    (BATCH*NPT)   // 16384

// ---------------------------------------------------------------------------
// FINAL CONFIG (r17, proven 188.2 µs):
//   knnqkv fused (3072 blocks, g%3: 2 knn + 1 qkv)  ~146 µs
//   attn (1 wave/point, DPP softmax)                ~25 µs
//   proj (16 rows/block, 4 rows/thread, in-place)   ~18 µs
// knn: r13 full scan, QPW=2, DPP insert shift — 82% VALU issue-bound,
// within ~20% of its ~2850-instr/query structural floor. Four pruning
// attempts (3-D grid x2, tail-free, z-slab) all lost: selection is
// insert-bound (16·ln(N/16) inserts), so candidate pruning buys little
// while its traversal costs latency. Fusions beyond this config lost too
// (r18 attn+proj, r19 residency-matched, r20 LDS-qkv).
// ---------------------------------------------------------------------------
#define TILE 1024
#define QPW  2
#define NWV  4
#define KNNB (BN/(NWV*QPW))      // 2048
#define QKVB (BN/16)             // 1024 (16 rows/block, 2 rows/thread)

__device__ __forceinline__ float readlane_f(float v, int l) {
  return __int_as_float(__builtin_amdgcn_readlane(__float_as_int(v), l));
}
// DPP row_shr:1 — lane i reads lane i-1 within its 16-lane row (VALU pipe).
__device__ __forceinline__ float dpp_shr1_f(float x) {
  return __int_as_float(__builtin_amdgcn_update_dpp(
      __float_as_int(x), __float_as_int(x), 0x111, 0xF, 0xF, false));
}
__device__ __forceinline__ int dpp_shr1_i(int x) {
  return __builtin_amdgcn_update_dpp(x, x, 0x111, 0xF, 0xF, false);
}
__device__ __forceinline__ float f4c(const float4 v, int u) {
  return u == 0 ? v.x : u == 1 ? v.y : u == 2 ? v.z : v.w;
}

__global__ __launch_bounds__(256) void knnqkv_kernel(
    const float* __restrict__ xyz, int* __restrict__ knn_out,
    const float* __restrict__ x,
    const float* __restrict__ Wq, const float* __restrict__ bq,
    const float* __restrict__ Wk, const float* __restrict__ bk,
    const float* __restrict__ Wv, const float* __restrict__ bv,
    float* __restrict__ q, float* __restrict__ k, float* __restrict__ v) {
  __shared__ float4 sbuf[TILE];   // 16 KB, shared by both paths
  const int g   = blockIdx.x;
  const int tid = threadIdx.x;

  if (g % 3 != 2) {
    // =================== KNN path (r13 body, 2048 blocks) ===================
    const int kb_  = (g/3)*2 + (g%3);
    const int lane = tid & 63;
    const int wave = tid >> 6;
    const int qbase = kb_ * (NWV*QPW) + wave * QPW;
    const int b = qbase / NPT;

    float qx[QPW], qy[QPW], qz[QPW], qsq[QPW];
    float topd[QPW]; int topi[QPW]; float tau[QPW];
#pragma unroll
    for (int qi = 0; qi < QPW; ++qi) {
      const int gg = qbase + qi;
      qx[qi] = xyz[(size_t)gg*3+0];
      qy[qi] = xyz[(size_t)gg*3+1];
      qz[qi] = xyz[(size_t)gg*3+2];
      qsq[qi] = __fadd_rn(__fadd_rn(__fmul_rn(qx[qi],qx[qi]),
                                    __fmul_rn(qy[qi],qy[qi])),
                          __fmul_rn(qz[qi],qz[qi]));
      topd[qi] = 3e38f; topi[qi] = 0; tau[qi] = 3e38f;
    }

    for (int t = 0; t < NPT/TILE; ++t) {
      __syncthreads();
      const float* src = xyz + (size_t)(b*NPT + t*TILE)*3;
      for (int i = tid; i < TILE; i += 256) {
        const float xx = src[i*3+0], yy = src[i*3+1], zz = src[i*3+2];
        const float sq = __fadd_rn(__fadd_rn(__fmul_rn(xx,xx), __fmul_rn(yy,yy)),
                                   __fmul_rn(zz,zz));
        sbuf[i] = make_float4(xx+xx, yy+yy, zz+zz, sq);
      }
      __syncthreads();

      for (int c = 0; c < TILE/64; ++c) {
        const float4 cd = sbuf[c*64 + lane];
        const int cbase = t*TILE + c*64;
#pragma unroll
        for (int qi = 0; qi < QPW; ++qi) {
          float dot2 = __fadd_rn(__fadd_rn(__fmul_rn(qx[qi],cd.x),
                                           __fmul_rn(qy[qi],cd.y)),
                                 __fmul_rn(qz[qi],cd.z));
          float d2 = __fsub_rn(__fadd_rn(qsq[qi], cd.w), dot2);
          unsigned long long m = __ballot(d2 < tau[qi]);
          while (m) {
            const int l = (int)__builtin_ctzll(m);
            const float dn = readlane_f(d2, l);
            const int   ni_ = cbase + l;
            const float my  = topd[qi];
            const int   myi = topi[qi];
            float ab  = dpp_shr1_f(my);
            int   abi = dpp_shr1_i(myi);
            if (lane == 0) ab = -3e38f;
            const bool ge = dn < my;
            const bool gt = dn < ab;
            topd[qi] = ge ? (gt ? ab  : dn ) : my;
            topi[qi] = ge ? (gt ? abi : ni_) : myi;
            tau[qi] = readlane_f(topd[qi], 15);
            m &= (m - 1);
            if (m) m &= __ballot(d2 < tau[qi]);
          }
        }
      }
    }

#pragma unroll
    for (int qi = 0; qi < QPW; ++qi) {
      if (lane < KNN_K) knn_out[(size_t)(qbase + qi)*KNN_K + lane] = topi[qi];
    }
  } else {
    // =================== QKV path (r5 body, 1024 blocks) ===================
    float* xs = (float*)sbuf;       // 16 rows x 128 = 8 KB
    const int qb_ = g/3;
    const int rowbase = qb_ * 16;
    {
      float4* xs4 = (float4*)xs;
      const float4* src4 = (const float4*)(x + (size_t)rowbase*DIMC);
      for (int i = tid; i < 16*DIMC/4; i += 256) xs4[i] = src4[i];
    }
    __syncthreads();

    const int cg = tid & 31, rg = tid >> 5;
    const int c0 = cg * 4;
    float4 aq0 = *(const float4*)&bq[c0], aq1 = aq0;
    float4 ak0 = *(const float4*)&bk[c0], ak1 = ak0;
    float4 av0 = *(const float4*)&bv[c0], av1 = av0;

    for (int kk = 0; kk < DIMC; kk += 4) {
      const float4 xa = *(const float4*)&xs[rg*DIMC + kk];
      const float4 xb = *(const float4*)&xs[(rg+8)*DIMC + kk];
#pragma unroll
      for (int u = 0; u < 4; ++u) {
        const float4 wq = *(const float4*)&Wq[(size_t)(kk+u)*DIMC + c0];
        const float4 wk = *(const float4*)&Wk[(size_t)(kk+u)*DIMC + c0];
        const float4 wv = *(const float4*)&Wv[(size_t)(kk+u)*DIMC + c0];
        const float xau = f4c(xa, u), xbu = f4c(xb, u);
        aq0.x = fmaf(xau, wq.x, aq0.x); aq0.y = fmaf(xau, wq.y, aq0.y);
        aq0.z = fmaf(xau, wq.z, aq0.z); aq0.w = fmaf(xau, wq.w, aq0.w);
        aq1.x = fmaf(xbu, wq.x, aq1.x); aq1.y = fmaf(xbu, wq.y, aq1.y);
        aq1.z = fmaf(xbu, wq.z, aq1.z); aq1.w = fmaf(xbu, wq.w, aq1.w);
        ak0.x = fmaf(xau, wk.x, ak0.x); ak0.y = fmaf(xau, wk.y, ak0.y);
        ak0.z = fmaf(xau, wk.z, ak0.z); ak0.w = fmaf(xau, wk.w, ak0.w);
        ak1.x = fmaf(xbu, wk.x, ak1.x); ak1.y = fmaf(xbu, wk.y, ak1.y);
        ak1.z = fmaf(xbu, wk.z, ak1.z); ak1.w = fmaf(xbu, wk.w, ak1.w);
        av0.x = fmaf(xau, wv.x, av0.x); av0.y = fmaf(xau, wv.y, av0.y);
        av0.z = fmaf(xau, wv.z, av0.z); av0.w = fmaf(xau, wv.w, av0.w);
        av1.x = fmaf(xbu, wv.x, av1.x); av1.y = fmaf(xbu, wv.y, av1.y);
        av1.z = fmaf(xbu, wv.z, av1.z); av1.w = fmaf(xbu, wv.w, av1.w);
      }
    }

    const size_t r0 = (size_t)(rowbase + rg)*DIMC + c0;
    const size_t r1 = (size_t)(rowbase + rg + 8)*DIMC + c0;
    *(float4*)&q[r0] = aq0; *(float4*)&q[r1] = aq1;
    *(float4*)&k[r0] = ak0; *(float4*)&k[r1] = ak1;
    *(float4*)&v[r0] = av0; *(float4*)&v[r1] = av1;
  }
}

// ---------------------------------------------------------------------------
// DPP ring-rotate move (VALU, no DS pipe): lane i of each 16-lane row reads
// lane (i+N)%16. Ring all-reduce with N=1,2,4,8 covers all 16 lanes.
// ---------------------------------------------------------------------------
template <int CTRL>
__device__ __forceinline__ float dppf(float x) {
  return __int_as_float(__builtin_amdgcn_update_dpp(
      __float_as_int(x), __float_as_int(x), CTRL, 0xF, 0xF, false));
}
#define ROR1 0x121
#define ROR2 0x122
#define ROR4 0x124
#define ROR8 0x128

// ---------------------------------------------------------------------------
// Kernel 2: gather + bias MLP + attention. ONE WAVE PER POINT.
// ---------------------------------------------------------------------------
__global__ __launch_bounds__(256) void attn_kernel(const float* __restrict__ xyz,
    const int* __restrict__ knn, const float* __restrict__ qb,
    const float* __restrict__ kb, const float* __restrict__ vb,
    const float* __restrict__ W1, const float* __restrict__ b1,
    const float* __restrict__ W2, const float* __restrict__ b2,
    float* __restrict__ ao) {
  __shared__ float sw[4][NH][KNN_K];
  __shared__ int   sn[4][KNN_K];
  const int tid  = threadIdx.x;
  const int wave = tid >> 6;
  const int lane = tid & 63;
  const int p = blockIdx.x * 4 + wave;
  const int b = p / NPT;
  const int h = lane >> 4;
  const int j = lane & 15;

  const int nj = knn[(size_t)p*KNN_K + j];
  if (h == 0) sn[wave][j] = nj;
  const size_t nn = (size_t)b*NPT + nj;

  const float qx0 = xyz[(size_t)p*3+0];
  const float qy0 = xyz[(size_t)p*3+1];
  const float qz0 = xyz[(size_t)p*3+2];
  const float rx = qx0 - xyz[nn*3+0];
  const float ry = qy0 - xyz[nn*3+1];
  const float rz = qz0 - xyz[nn*3+2];
  float bias = b2[h];
#pragma unroll 8
  for (int u = 0; u < HID; ++u) {
    float hv = rx*W1[0*HID+u] + ry*W1[1*HID+u] + rz*W1[2*HID+u] + b1[u];
    hv = hv > 0.f ? hv : 0.f;
    bias = fmaf(hv, W2[u*NH + h], bias);
  }

  const float* qrow = qb + (size_t)p*DIMC + h*32;
  const float* krow = kb + nn*DIMC + h*32;
  float s = 0.f;
#pragma unroll
  for (int u = 0; u < 32; u += 4) {
    const float4 qv = *(const float4*)(qrow + u);
    const float4 kv = *(const float4*)(krow + u);
    s = fmaf(qv.x, kv.x, s); s = fmaf(qv.y, kv.y, s);
    s = fmaf(qv.z, kv.z, s); s = fmaf(qv.w, kv.w, s);
  }
  s = s * 0.17677669529663689f + bias;   // 1/sqrt(32)

  float m = s;
  m = fmaxf(m, dppf<ROR1>(m));
  m = fmaxf(m, dppf<ROR2>(m));
  m = fmaxf(m, dppf<ROR4>(m));
  m = fmaxf(m, dppf<ROR8>(m));
  const float e = expf(s - m);
  float ssum = e;
  ssum += dppf<ROR1>(ssum);
  ssum += dppf<ROR2>(ssum);
  ssum += dppf<ROR4>(ssum);
  ssum += dppf<ROR8>(ssum);
  sw[wave][h][j] = e / ssum;

  __syncthreads();

  const int d0 = lane;
  const int hA = d0 >> 5;
  float out0 = 0.f, out1 = 0.f;
  const float* vbase = vb + (size_t)b*NPT*DIMC;
#pragma unroll 4
  for (int j2 = 0; j2 < KNN_K; ++j2) {
    const int n = sn[wave][j2];
    const float wA = sw[wave][hA][j2];
    const float wB = sw[wave][2+hA][j2];
    const float* vrow = vbase + (size_t)n*DIMC;
    out0 = fmaf(wA, vrow[d0],    out0);
    out1 = fmaf(wB, vrow[64+d0], out1);
  }
  ao[(size_t)p*DIMC + d0]      = out0;
  ao[(size_t)p*DIMC + 64 + d0] = out1;
}

// ---------------------------------------------------------------------------
// Kernel 3: output projection, 4 rows/thread, 16 rows/block, IN-PLACE on
// d_out.
// ---------------------------------------------------------------------------
#define PROJ_ROWS 16

__global__ __launch_bounds__(128) void proj_kernel(float* __restrict__ inout,
    const float* __restrict__ Wo, const float* __restrict__ bo) {
  __shared__ float xs[PROJ_ROWS*DIMC];   // 8 KB
  const int tid = threadIdx.x;
  const int rowbase = blockIdx.x * PROJ_ROWS;
  {
    float4* xs4 = (float4*)xs;
    const float4* src4 = (const float4*)(inout + (size_t)rowbase*DIMC);
    for (int i = tid; i < PROJ_ROWS*DIMC/4; i += 128) xs4[i] = src4[i];
  }
  __syncthreads();

  const int cg = tid & 31, rg = tid >> 5;   // rg 0..3
  const int c0 = cg * 4;
  float4 a[4];
  {
    const float4 bo4 = *(const float4*)&bo[c0];
#pragma unroll
    for (int i = 0; i < 4; ++i) a[i] = bo4;
  }

  for (int kk = 0; kk < DIMC; kk += 4) {
    float4 xr[4];
#pragma unroll
    for (int i = 0; i < 4; ++i)
      xr[i] = *(const float4*)&xs[(rg + 4*i)*DIMC + kk];
#pragma unroll
    for (int u = 0; u < 4; ++u) {
      const float4 w = *(const float4*)&Wo[(size_t)(kk+u)*DIMC + c0];
#pragma unroll
      for (int i = 0; i < 4; ++i) {
        const float xv = f4c(xr[i], u);
        a[i].x = fmaf(xv, w.x, a[i].x); a[i].y = fmaf(xv, w.y, a[i].y);
        a[i].z = fmaf(xv, w.z, a[i].z); a[i].w = fmaf(xv, w.w, a[i].w);
      }
    }
  }

#pragma unroll
  for (int i = 0; i < 4; ++i)
    *(float4*)&inout[(size_t)(rowbase + rg + 4*i)*DIMC + c0] = a[i];
}

// ---------------------------------------------------------------------------
extern "C" void kernel_launch(void* const* d_in, const int* in_sizes, int n_in,
                              void* d_out, int out_size, void* d_ws, size_t ws_size,
                              hipStream_t stream) {
  const float* x   = (const float*)d_in[0];
  const float* xyz = (const float*)d_in[1];
  const float* Wq  = (const float*)d_in[2];
  const float* bq  = (const float*)d_in[3];
  const float* Wk  = (const float*)d_in[4];
  const float* bk  = (const float*)d_in[5];
  const float* Wv  = (const float*)d_in[6];
  const float* bv  = (const float*)d_in[7];
  const float* Wo  = (const float*)d_in[8];
  const float* bo  = (const float*)d_in[9];
  const float* W1  = (const float*)d_in[10];
  const float* b1  = (const float*)d_in[11];
  const float* W2  = (const float*)d_in[12];
  const float* b2  = (const float*)d_in[13];
  float* out = (float*)d_out;

  // workspace layout (bytes): knn idx 1MB | q 8MB | k 8MB | v 8MB  => 25MB
  char* ws = (char*)d_ws;
  int*   knn = (int*)ws;
  float* q   = (float*)(ws + (size_t)(1u<<20));
  float* k   = (float*)(ws + (size_t)9*(1u<<20));
  float* v   = (float*)(ws + (size_t)17*(1u<<20));

  // grid = KNNB + QKVB = 3072 exactly (2 knn + 1 qkv per g-triple)
  hipLaunchKernelGGL(knnqkv_kernel, dim3(KNNB + QKVB), dim3(256), 0, stream,
                     xyz, knn, x, Wq, bq, Wk, bk, Wv, bv, q, k, v);
  hipLaunchKernelGGL(attn_kernel, dim3(BN/4), dim3(256), 0, stream,
                     xyz, knn, q, k, v, W1, b1, W2, b2, out);
  hipLaunchKernelGGL(proj_kernel, dim3(BN/PROJ_ROWS), dim3(128), 0, stream,
                     out, Wo, bo);
}